// Round 5
// baseline (443.158 us; speedup 1.0000x reference)
//
#include <hip/hip_runtime.h>

#define B_  8
#define C_  128
#define H_  128
#define W_  256
#define HW_ (H_ * W_)
#define TH  8
#define TW  32
#define S2S 40                    // f2 row stride (dwords) — 2-way banks, free
#define S1S 32                    // f1 row stride (dwords) — 2-way banks, free
#define S1OFF (16 * S2S)          // 640 (f2 tile = 16 rows)
#define PAIRN (S1OFF + TH * S1S)  // 896 dwords per channel-pair tile
#define NTHREADS 576

typedef __fp16 h2 __attribute__((ext_vector_type(2)));

__device__ __forceinline__ float dot2f16(unsigned int a, unsigned int b, float c) {
#if __has_builtin(__builtin_amdgcn_fdot2)
    return __builtin_amdgcn_fdot2(__builtin_bit_cast(h2, a),
                                  __builtin_bit_cast(h2, b), c, false);
#else
    h2 ha = __builtin_bit_cast(h2, a), hb = __builtin_bit_cast(h2, b);
    return c + (float)ha.x * (float)hb.x + (float)ha.y * (float)hb.y;
#endif
}

__device__ __forceinline__ unsigned int pk(float x, float y) {
    h2 r = __builtin_amdgcn_cvt_pkrtz(x, y);
    return __builtin_bit_cast(unsigned int, r);
}

// 9-wave block, wave = di. TH=8 tile -> acc[9][4]=36 regs -> 2 blocks/CU.
// Depth-2 pipeline, raw s_barrier + lgkmcnt(0) only (counted vmcnt on loads).
// Stage = 4 channels (2 f16x2 pairs). Waves 0-4 stage f2, 5-6 stage f1,
// 7-8 compute-only.
__global__ __launch_bounds__(NTHREADS, 5) void cv_kernel(
    const float* __restrict__ f1g, const float* __restrict__ f2g,
    float* __restrict__ outg) {
    __shared__ __align__(16) unsigned int lds[2][2][PAIRN];

    const int tid = threadIdx.x;
    const int w0 = blockIdx.x * TW;
    const int h0 = blockIdx.y * TH;
    const int b  = blockIdx.z;

    // ---- staging roles (wave-uniform) ----
    const bool stg = (tid < 448);
    int off0 = 0, ld0 = 0, pp = 0;
    float m0 = 0.f;
    const float* p0 = f1g;
    if (tid < 320) {                       // waves 0-4: f2 tile 16r x 10 col4 x 2 pairs
        pp = tid / 160;
        int slot = tid % 160;
        int r = slot / 10, c4 = slot % 10;
        int gh = h0 - 4 + r, gw = w0 - 4 + 4 * c4;
        bool valid = (gh >= 0) && (gh < H_) && (gw >= 0) && (gw <= W_ - 4);
        int ghc = min(max(gh, 0), H_ - 1);
        int gwc = min(max(gw, 0), W_ - 4);
        off0 = ((b * C_ + 2 * pp) * H_ + ghc) * W_ + gwc;
        p0   = f2g;
        ld0  = r * S2S + 4 * c4;
        m0   = valid ? 1.f : 0.f;
    } else if (tid < 448) {                // waves 5-6: f1 tile 8r x 8 col4 x 2 pairs
        int u = tid - 320;
        pp = u / 64;
        int slot = u % 64;
        int r = slot / 8, c4 = slot % 8;
        off0 = ((b * C_ + 2 * pp) * H_ + h0 + r) * W_ + w0 + 4 * c4;
        p0   = f1g;
        ld0  = S1OFF + r * S1S + 4 * c4;
        m0   = 1.f;
    }

#define LOADST(Sa, Sb)                                                        \
    do {                                                                      \
        if (stg) {                                                            \
            Sa = *(const float4*)(p0 + off0);                                 \
            Sb = *(const float4*)(p0 + off0 + HW_);                           \
            off0 += 4 * HW_;                                                  \
        }                                                                     \
    } while (0)

#define STOREST(bi, Sa, Sb)                                                   \
    do {                                                                      \
        if (stg) {                                                            \
            uint4 wv;                                                         \
            wv.x = pk(Sa.x * m0, Sb.x * m0);                                  \
            wv.y = pk(Sa.y * m0, Sb.y * m0);                                  \
            wv.z = pk(Sa.z * m0, Sb.z * m0);                                  \
            wv.w = pk(Sa.w * m0, Sb.w * m0);                                  \
            *(uint4*)(&lds[bi][pp][ld0]) = wv;                                \
        }                                                                     \
    } while (0)

#define BAR()                                                                 \
    do {                                                                      \
        asm volatile("s_waitcnt lgkmcnt(0)" ::: "memory");                    \
        __builtin_amdgcn_s_barrier();                                         \
    } while (0)

    // ---- compute mapping ----
    const int di   = tid >> 6;             // 0..8
    const int lane = tid & 63;
    const int hh   = lane >> 3;            // 0..7
    const int sc   = lane & 7;             // 0..7, 4-px strip
    const int rdF2 = (hh + di) * S2S + 4 * sc;
    const int rdF1 = S1OFF + hh * S1S + 4 * sc;

    float acc[9][4];
#pragma unroll
    for (int j = 0; j < 9; ++j)
#pragma unroll
        for (int p = 0; p < 4; ++p) acc[j][p] = 0.f;

#define COMPUTE(bi)                                                           \
    do {                                                                      \
        _Pragma("unroll")                                                     \
        for (int q = 0; q < 2; ++q) {                                         \
            const unsigned int* buf = lds[bi][q];                             \
            uint4 fa = *(const uint4*)(buf + rdF2);                           \
            uint4 fb = *(const uint4*)(buf + rdF2 + 4);                       \
            uint4 fc = *(const uint4*)(buf + rdF2 + 8);                       \
            uint4 ga = *(const uint4*)(buf + rdF1);                           \
            unsigned int f2u[12] = {fa.x, fa.y, fa.z, fa.w, fb.x, fb.y,       \
                                    fb.z, fb.w, fc.x, fc.y, fc.z, fc.w};      \
            unsigned int f1u[4]  = {ga.x, ga.y, ga.z, ga.w};                  \
            _Pragma("unroll")                                                 \
            for (int j = 0; j < 9; ++j)                                       \
                _Pragma("unroll")                                             \
                for (int p = 0; p < 4; ++p)                                   \
                    acc[j][p] = dot2f16(f1u[p], f2u[p + j], acc[j][p]);       \
        }                                                                     \
    } while (0)

    float4 aA, bA, aB, bB;

    // prologue: stages 0,1 in flight; stage 0 -> LDS buf0
    LOADST(aA, bA);                    // stage 0
    LOADST(aB, bB);                    // stage 1
    STOREST(0, aA, bA);                // waits stage-0 loads only (counted)
    BAR();

    for (int s = 0; s < 30; s += 2) {
        LOADST(aA, bA);                // stage s+2 (in flight through compute)
        COMPUTE(0);                    // stage s
        STOREST(1, aB, bB);            // stage s+1
        BAR();
        LOADST(aB, bB);                // stage s+3
        COMPUTE(1);                    // stage s+1
        STOREST(0, aA, bA);            // stage s+2
        BAR();
    }
    COMPUTE(0);                        // stage 30
    STOREST(1, aB, bB);                // stage 31
    BAR();
    COMPUTE(1);                        // stage 31

    // ---- epilogue: mean over C and store ----
    const float inv = 1.0f / 128.0f;
    int obase = ((b * 81 + di * 9) * H_ + h0 + hh) * W_ + w0 + 4 * sc;
#pragma unroll
    for (int j = 0; j < 9; ++j) {
        float4 o = make_float4(acc[j][0] * inv, acc[j][1] * inv,
                               acc[j][2] * inv, acc[j][3] * inv);
        *(float4*)(outg + obase) = o;
        obase += HW_;
    }
}

extern "C" void kernel_launch(void* const* d_in, const int* in_sizes, int n_in,
                              void* d_out, int out_size, void* d_ws, size_t ws_size,
                              hipStream_t stream) {
    const float* f1 = (const float*)d_in[0];
    const float* f2 = (const float*)d_in[1];
    float* out = (float*)d_out;
    dim3 grid(W_ / TW, H_ / TH, B_);   // 8 x 16 x 8 = 1024 blocks
    cv_kernel<<<grid, NTHREADS, 0, stream>>>(f1, f2, out);
}

// Round 6
// 155.128 us; speedup vs baseline: 2.8567x; 2.8567x over previous
//
#include <hip/hip_runtime.h>

#define B_  8
#define C_  128
#define H_  128
#define W_  256
#define HW_ (H_ * W_)
#define TH  8
#define TW  32
#define S2S 40                    // f2 row stride (dwords): 40%32=8 -> 2-way, free
#define S1S 40                    // f1 row stride (dwords): same
#define S1OFF (16 * S2S)          // 640 (f2 tile = 16 rows)
#define PAIRN (S1OFF + TH * S1S)  // 960 dwords per channel-pair tile
#define NTHREADS 576

typedef __fp16 h2 __attribute__((ext_vector_type(2)));

__device__ __forceinline__ float dot2f16(unsigned int a, unsigned int b, float c) {
#if __has_builtin(__builtin_amdgcn_fdot2)
    return __builtin_amdgcn_fdot2(__builtin_bit_cast(h2, a),
                                  __builtin_bit_cast(h2, b), c, false);
#else
    h2 ha = __builtin_bit_cast(h2, a), hb = __builtin_bit_cast(h2, b);
    return c + (float)ha.x * (float)hb.x + (float)ha.y * (float)hb.y;
#endif
}

__device__ __forceinline__ unsigned int pk(float x, float y) {
    h2 r = __builtin_amdgcn_cvt_pkrtz(x, y);
    return __builtin_bit_cast(unsigned int, r);
}

// 9-wave block, wave = di, TH=8 tile -> acc[9][4] = 36 regs.
// Depth-2.5 pipeline: loads for stage s+2 issued before compute of stage s;
// the LDS-write of s+1 waits only its own loads (compiler-counted vmcnt);
// barrier = s_waitcnt lgkmcnt(0) + raw s_barrier -> global loads stay in
// flight across barriers (no vmcnt(0) drain).
// Stage = 4 channels (2 f16x2 pairs). Waves 0-4 stage f2, 5-6 stage f1,
// 7-8 compute-only. bounds(576,3): generous 170-reg cap (round-3-proven
// allocation point; rounds 4/5 showed tighter caps cause GB-scale spills).
__global__ __launch_bounds__(NTHREADS, 3) void cv_kernel(
    const float* __restrict__ f1g, const float* __restrict__ f2g,
    float* __restrict__ outg) {
    __shared__ __align__(16) unsigned int lds[2][2][PAIRN];

    const int tid = threadIdx.x;
    const int w0 = blockIdx.x * TW;
    const int h0 = blockIdx.y * TH;
    const int b  = blockIdx.z;

    // ---- staging roles (wave-uniform) ----
    const bool stg = (tid < 448);
    int off0 = 0, ld0 = 0, pp = 0;
    float m0 = 0.f;
    const float* p0 = f1g;
    if (tid < 320) {                 // waves 0-4: f2 tile 16r x 10 col4 x 2 pairs
        pp = tid / 160;
        int slot = tid % 160;
        int r = slot / 10, c4 = slot % 10;
        int gh = h0 - 4 + r, gw = w0 - 4 + 4 * c4;
        // halo = 4 = float4 width -> each float4 is entirely in or out
        bool valid = (gh >= 0) && (gh < H_) && (gw >= 0) && (gw <= W_ - 4);
        int ghc = min(max(gh, 0), H_ - 1);
        int gwc = min(max(gw, 0), W_ - 4);
        off0 = ((b * C_ + 2 * pp) * H_ + ghc) * W_ + gwc;
        p0   = f2g;
        ld0  = r * S2S + 4 * c4;
        m0   = valid ? 1.f : 0.f;
    } else if (tid < 448) {          // waves 5-6: f1 tile 8r x 8 col4 x 2 pairs
        int u = tid - 320;
        pp = u / 64;
        int slot = u % 64;
        int r = slot / 8, c4 = slot % 8;
        off0 = ((b * C_ + 2 * pp) * H_ + h0 + r) * W_ + w0 + 4 * c4;
        p0   = f1g;
        ld0  = S1OFF + r * S1S + 4 * c4;
        m0   = 1.f;
    }

#define LOADST(Sa, Sb)                                                        \
    do {                                                                      \
        if (stg) {                                                            \
            Sa = *(const float4*)(p0 + off0);                                 \
            Sb = *(const float4*)(p0 + off0 + HW_);                           \
            off0 += 4 * HW_;                                                  \
        }                                                                     \
    } while (0)

#define STOREST(bi, Sa, Sb)                                                   \
    do {                                                                      \
        if (stg) {                                                            \
            uint4 wv;                                                         \
            wv.x = pk(Sa.x * m0, Sb.x * m0);                                  \
            wv.y = pk(Sa.y * m0, Sb.y * m0);                                  \
            wv.z = pk(Sa.z * m0, Sb.z * m0);                                  \
            wv.w = pk(Sa.w * m0, Sb.w * m0);                                  \
            *(uint4*)(&lds[bi][pp][ld0]) = wv;                                \
        }                                                                     \
    } while (0)

#define BAR()                                                                 \
    do {                                                                      \
        asm volatile("s_waitcnt lgkmcnt(0)" ::: "memory");                    \
        __builtin_amdgcn_s_barrier();                                         \
    } while (0)

    // ---- compute mapping ----
    const int di   = tid >> 6;       // 0..8
    const int lane = tid & 63;
    const int hh   = lane >> 3;      // 0..7
    const int sc   = lane & 7;       // 0..7, 4-px strip
    const int rdF2 = (hh + di) * S2S + 4 * sc;
    const int rdF1 = S1OFF + hh * S1S + 4 * sc;

    float acc[9][4];
#pragma unroll
    for (int j = 0; j < 9; ++j)
#pragma unroll
        for (int p = 0; p < 4; ++p) acc[j][p] = 0.f;

#define COMPUTE(bi)                                                           \
    do {                                                                      \
        _Pragma("unroll")                                                     \
        for (int q = 0; q < 2; ++q) {                                         \
            const unsigned int* buf = lds[bi][q];                             \
            uint4 fa = *(const uint4*)(buf + rdF2);                           \
            uint4 fb = *(const uint4*)(buf + rdF2 + 4);                       \
            uint4 fc = *(const uint4*)(buf + rdF2 + 8);                       \
            uint4 ga = *(const uint4*)(buf + rdF1);                           \
            unsigned int f2u[12] = {fa.x, fa.y, fa.z, fa.w, fb.x, fb.y,       \
                                    fb.z, fb.w, fc.x, fc.y, fc.z, fc.w};      \
            unsigned int f1u[4]  = {ga.x, ga.y, ga.z, ga.w};                  \
            _Pragma("unroll")                                                 \
            for (int j = 0; j < 9; ++j)                                       \
                _Pragma("unroll")                                             \
                for (int p = 0; p < 4; ++p)                                   \
                    acc[j][p] = dot2f16(f1u[p], f2u[p + j], acc[j][p]);       \
        }                                                                     \
    } while (0)

    float4 aA, bA, aB, bB;

    // prologue: stages 0,1 in flight; stage 0 -> LDS buf0
    LOADST(aA, bA);                  // stage 0
    LOADST(aB, bB);                  // stage 1
    STOREST(0, aA, bA);              // waits stage-0 loads only (counted)
    BAR();

    for (int s = 0; s < 30; s += 2) {
        LOADST(aA, bA);              // stage s+2 (in flight through compute)
        COMPUTE(0);                  // stage s
        STOREST(1, aB, bB);          // stage s+1
        BAR();
        LOADST(aB, bB);              // stage s+3
        COMPUTE(1);                  // stage s+1
        STOREST(0, aA, bA);          // stage s+2
        BAR();
    }
    COMPUTE(0);                      // stage 30
    STOREST(1, aB, bB);              // stage 31
    BAR();
    COMPUTE(1);                      // stage 31

    // ---- epilogue: mean over C and store ----
    const float inv = 1.0f / 128.0f;
    int obase = ((b * 81 + di * 9) * H_ + h0 + hh) * W_ + w0 + 4 * sc;
#pragma unroll
    for (int j = 0; j < 9; ++j) {
        float4 o = make_float4(acc[j][0] * inv, acc[j][1] * inv,
                               acc[j][2] * inv, acc[j][3] * inv);
        *(float4*)(outg + obase) = o;
        obase += HW_;
    }
}

extern "C" void kernel_launch(void* const* d_in, const int* in_sizes, int n_in,
                              void* d_out, int out_size, void* d_ws, size_t ws_size,
                              hipStream_t stream) {
    const float* f1 = (const float*)d_in[0];
    const float* f2 = (const float*)d_in[1];
    float* out = (float*)d_out;
    dim3 grid(W_ / TW, H_ / TH, B_);   // 8 x 16 x 8 = 1024 blocks
    cv_kernel<<<grid, NTHREADS, 0, stream>>>(f1, f2, out);
}